// Round 11
// baseline (188.947 us; speedup 1.0000x reference)
//
#include <hip/hip_runtime.h>
#include <math.h>

#define D 768
#define DOUT 384
#define LSEQ 512
#define BATCH 4
#define KTOP 51
#define EPS 1e-5f

typedef unsigned short ushort_t;
typedef __bf16 bf16x8 __attribute__((ext_vector_type(8)));
typedef float f32x4 __attribute__((ext_vector_type(4)));

// global->LDS direct DMA, 16B per lane. LDS dest is wave-uniform base + lane*16.
#define GLOAD16(gp, lp)                                                        \
    __builtin_amdgcn_global_load_lds(                                          \
        (const __attribute__((address_space(1))) unsigned int*)(gp),           \
        (__attribute__((address_space(3))) unsigned int*)(lp), 16, 0, 0)

// fp32 -> bf16 round-to-nearest-even (inputs are finite; NaN path not needed)
__device__ __forceinline__ ushort_t f2bf(float f) {
    unsigned int u = __builtin_bit_cast(unsigned int, f);
    u = (u + 0x7FFFu + ((u >> 16) & 1u)) >> 16;
    return (ushort_t)u;
}

__device__ __forceinline__ float bf2f(ushort_t u) {
    unsigned int v = ((unsigned int)u) << 16;
    return __builtin_bit_cast(float, v);
}

// ---------------------------------------------------------------------------
// Prep: blocks [0,1536) convert hidden fp32->bf16; blocks [1536,2688) do the
// two 768x768 W transposes; block 2688 zeroes pooled/z accumulators + fc
// completion counter (graph-safe: re-zeroed every call).
// ---------------------------------------------------------------------------
__global__ __launch_bounds__(256) void prep_kernel(const float* __restrict__ hidden,
                                                   ushort_t* __restrict__ Ah,
                                                   const float* __restrict__ W0,
                                                   const float* __restrict__ W1,
                                                   ushort_t* __restrict__ WT0,
                                                   ushort_t* __restrict__ WT1,
                                                   float* __restrict__ pooled,
                                                   float* __restrict__ z,
                                                   int* __restrict__ fcnt) {
    __shared__ float tile[32][33];
    const int bid = blockIdx.x;
    const int tid = threadIdx.x;
    if (bid < 1536) {
        const int i = (bid * 256 + tid) * 4;
        const float4 v = *(const float4*)(hidden + i);
        ushort4 o;
        o.x = f2bf(v.x); o.y = f2bf(v.y); o.z = f2bf(v.z); o.w = f2bf(v.w);
        *(ushort4*)(Ah + i) = o;
    } else if (bid < 2688) {
        const int t = bid - 1536;
        const int zz = t / 576;
        const int rem = t - zz * 576;
        const int by = rem / 24, bx = rem - by * 24;
        const float* W = zz ? W1 : W0;
        ushort_t* WT = zz ? WT1 : WT0;
        const int kbase = by * 32;
        const int nbase = bx * 32;
        const int r = tid >> 3, c4 = (tid & 7) * 4;

        const float4 v = *(const float4*)(W + (size_t)(kbase + r) * D + nbase + c4);
        tile[r][c4 + 0] = v.x; tile[r][c4 + 1] = v.y;
        tile[r][c4 + 2] = v.z; tile[r][c4 + 3] = v.w;
        __syncthreads();
        ushort4 o;
        o.x = f2bf(tile[c4 + 0][r]); o.y = f2bf(tile[c4 + 1][r]);
        o.z = f2bf(tile[c4 + 2][r]); o.w = f2bf(tile[c4 + 3][r]);
        *(ushort4*)(WT + (size_t)(nbase + r) * D + kbase + c4) = o;
    } else {
        for (int i = tid; i < BATCH * D; i += 256) pooled[i] = 0.f;
        for (int i = tid; i < BATCH * DOUT; i += 256) z[i] = 0.f;
        if (tid == 0) *fcnt = 0;
    }
}

// ---------------------------------------------------------------------------
// Feature GEMM (bf16 MFMA): A(2048x768) @ W(768x768) + bias.
// 64x64 tiles (wave = 32x32 quadrant, 2x2 frags): 768 blocks = 3 blocks/CU.
// z==0: W_src -> fsrc_bf (bf16). z==1: W_dst -> feat_dst (fp32).
// ---------------------------------------------------------------------------
__global__ __launch_bounds__(256) void feat_gemm_kernel(const ushort_t* __restrict__ Ah,
                                                        const ushort_t* __restrict__ WT0,
                                                        const float* __restrict__ b0,
                                                        ushort_t* __restrict__ Csrc_bf,
                                                        const ushort_t* __restrict__ WT1,
                                                        const float* __restrict__ b1,
                                                        float* __restrict__ Cdst) {
    const ushort_t* WT = blockIdx.z ? WT1 : WT0;
    const float* bias = blockIdx.z ? b1 : b0;

    __shared__ ushort_t As[64 * 32];
    __shared__ ushort_t Bs[64 * 32];

    const int tid = threadIdx.x;
    const int lane = tid & 63;
    const int wave = tid >> 6;
    const int quad = lane >> 4;
    const int m15 = lane & 15;
    const int qRow = (wave & 1) * 32;
    const int qCol = (wave >> 1) * 32;

    const int rowBase = blockIdx.y * 64;
    const int colBase = blockIdx.x * 64;

    const int e0 = tid * 8;          // covers 64*32 = 2048 elems
    const int r0 = e0 >> 5;
    const int c0 = e0 & 31;
    const ushort_t* Abase = Ah + (size_t)rowBase * D;
    const ushort_t* Bbase = WT + (size_t)colBase * D;

    f32x4 acc[2][2] = {};

    for (int kk = 0; kk < D; kk += 32) {
        __syncthreads();
        GLOAD16(Abase + (size_t)r0 * D + kk + c0, &As[e0]);
        GLOAD16(Bbase + (size_t)r0 * D + kk + c0, &Bs[e0]);
        __syncthreads();

        bf16x8 a[2], b[2];
#pragma unroll
        for (int i = 0; i < 2; ++i)
            a[i] = *(const bf16x8*)&As[(qRow + i * 16 + m15) * 32 + quad * 8];
#pragma unroll
        for (int j = 0; j < 2; ++j)
            b[j] = *(const bf16x8*)&Bs[(qCol + j * 16 + m15) * 32 + quad * 8];
#pragma unroll
        for (int i = 0; i < 2; ++i)
#pragma unroll
            for (int j = 0; j < 2; ++j)
                acc[i][j] = __builtin_amdgcn_mfma_f32_16x16x32_bf16(a[i], b[j], acc[i][j], 0, 0, 0);
    }

    // C/D layout: col=lane&15, row=quad*4+reg
    if (blockIdx.z == 0) {
#pragma unroll
        for (int j = 0; j < 2; ++j) {
            const int col = colBase + qCol + j * 16 + m15;
            const float bv = bias[col];
#pragma unroll
            for (int i = 0; i < 2; ++i) {
                ushort_t* Cp = Csrc_bf + (size_t)(rowBase + qRow + i * 16 + quad * 4) * D + col;
#pragma unroll
                for (int r = 0; r < 4; ++r)
                    Cp[(size_t)r * D] = f2bf(acc[i][j][r] + bv);
            }
        }
    } else {
#pragma unroll
        for (int j = 0; j < 2; ++j) {
            const int col = colBase + qCol + j * 16 + m15;
            const float bv = bias[col];
#pragma unroll
            for (int i = 0; i < 2; ++i) {
                float* Cp = Cdst + (size_t)(rowBase + qRow + i * 16 + quad * 4) * D + col;
#pragma unroll
                for (int r = 0; r < 4; ++r)
                    Cp[(size_t)r * D] = acc[i][j][r] + bv;
            }
        }
    }
}

// ---------------------------------------------------------------------------
// Score kernel (topk + transpose fused union dispatch):
//  blocks [0,1536): 32x32 bf16 tile transpose fsrc -> fsrcT (coalesced, LDS);
//  blocks [1536,3584): per row: statistical pre-filter top-51 (+exact
//  fallback), gather-dot-leaky scores, softmax, scatter bf16 probs into P,
//  seed gate[row] = gate_b. Both halves depend only on feat_gemm -> overlap.
// ---------------------------------------------------------------------------
__global__ __launch_bounds__(256) void score_kernel(const float* __restrict__ attn,
                                                    const ushort_t* __restrict__ fsrc_bf,
                                                    ushort_t* __restrict__ fsrcT,
                                                    const float* __restrict__ feat_dst,
                                                    const float* __restrict__ attn_vec,
                                                    const float* __restrict__ gate_b,
                                                    ushort_t* __restrict__ P,
                                                    float* __restrict__ gate) {
    const int bid = blockIdx.x;
    const int tid = threadIdx.x;

    __shared__ ushort_t ttile[32][33];
    __shared__ float vals[LSEQ];
    __shared__ float cval[320];
    __shared__ int   cidx[320];
    __shared__ int   nhi, outSlot;
    __shared__ float sc[KTOP];
    __shared__ int   kid[KTOP];
    __shared__ float kvv[KTOP];

    if (bid < 1536) {
        // -------- transpose branch: (512x768) -> (768x512) per batch --------
        const int b = bid / 384;
        const int rem = bid - b * 384;
        const int by = rem / 24, bx = rem - by * 24;
        const int cbase = bx * 32;   // over D
        const int rbase = by * 32;   // over L
        const int tr = tid >> 3, tc4 = (tid & 7) * 4;

        const ushort_t* Ib = fsrc_bf + (size_t)b * LSEQ * D;
        ushort_t* Ob = fsrcT + (size_t)b * D * LSEQ;

        const ushort4 v = *(const ushort4*)(Ib + (size_t)(rbase + tr) * D + cbase + tc4);
        ttile[tr][tc4 + 0] = v.x; ttile[tr][tc4 + 1] = v.y;
        ttile[tr][tc4 + 2] = v.z; ttile[tr][tc4 + 3] = v.w;
        __syncthreads();
        ushort4 o;
        o.x = ttile[tc4 + 0][tr]; o.y = ttile[tc4 + 1][tr];
        o.z = ttile[tc4 + 2][tr]; o.w = ttile[tc4 + 3][tr];
        *(ushort4*)(Ob + (size_t)(cbase + tr) * LSEQ + rbase + tc4) = o;
        return;
    }

    // ------------------------------ score branch ------------------------------
    const int row = bid - 1536;     // b*L + l
    const int b = row >> 9;
    const int lane = tid & 63;
    const int wave = tid >> 6;

    // zero this row of P; seed gate accumulator with bias
    ((unsigned int*)(P + (size_t)row * LSEQ))[tid] = 0u;
    if (tid == 0) { gate[row] = gate_b[0]; nhi = 0; outSlot = 0; }

    const float* a = attn + (size_t)row * LSEQ;
    const float v0 = a[tid];
    const float v1 = a[tid + 256];
    vals[tid] = v0;
    vals[tid + 256] = v1;
    __syncthreads();

    if (v0 > 0.75f) {
        const int s = atomicAdd(&nhi, 1);
        if (s < 320) { cval[s] = v0; cidx[s] = tid; }
    }
    if (v1 > 0.75f) {
        const int s = atomicAdd(&nhi, 1);
        if (s < 320) { cval[s] = v1; cidx[s] = tid + 256; }
    }
    __syncthreads();

    const int n = nhi;
    if (n >= KTOP && n <= 320) {
        // fast path: rank within survivor set == global rank for survivors
        if (tid < n) {
            const float v = cval[tid];
            const int e = cidx[tid];
            int r = 0;
            for (int j = 0; j < n; ++j) {
                const float u = cval[j];
                r += (u > v) || (u == v && cidx[j] < e);
            }
            if (r < KTOP) {
                const int s = atomicAdd(&outSlot, 1);
                kid[s] = e; kvv[s] = v;
            }
        }
    } else {
        // exact fallback for arbitrary inputs
#pragma unroll
        for (int e0 = 0; e0 < 2; ++e0) {
            const int e = tid + e0 * 256;
            const float v = vals[e];
            int r = 0;
            for (int j = 0; j < LSEQ; ++j) {
                const float u = vals[j];
                r += (u > v) || (u == v && j < e);
            }
            if (r < KTOP) {
                const int s = atomicAdd(&outSlot, 1);
                kid[s] = e; kvv[s] = v;
            }
        }
    }

    // per-lane register slices: chunk c=lane (all lanes), c=lane+64 (lanes<32)
    const float* fdp = feat_dst + (size_t)row * D;
    float fdr[16], avr[16];
    {
        const int d0 = lane * 8;
        const float4 f0 = *(const float4*)(fdp + d0);
        const float4 f1 = *(const float4*)(fdp + d0 + 4);
        const float4 a0 = *(const float4*)(attn_vec + d0);
        const float4 a1 = *(const float4*)(attn_vec + d0 + 4);
        fdr[0]=f0.x; fdr[1]=f0.y; fdr[2]=f0.z; fdr[3]=f0.w;
        fdr[4]=f1.x; fdr[5]=f1.y; fdr[6]=f1.z; fdr[7]=f1.w;
        avr[0]=a0.x; avr[1]=a0.y; avr[2]=a0.z; avr[3]=a0.w;
        avr[4]=a1.x; avr[5]=a1.y; avr[6]=a1.z; avr[7]=a1.w;
    }
    if (lane < 32) {
        const int d1 = (lane + 64) * 8;
        const float4 f0 = *(const float4*)(fdp + d1);
        const float4 f1 = *(const float4*)(fdp + d1 + 4);
        const float4 a0 = *(const float4*)(attn_vec + d1);
        const float4 a1 = *(const float4*)(attn_vec + d1 + 4);
        fdr[8]=f0.x; fdr[9]=f0.y; fdr[10]=f0.z; fdr[11]=f0.w;
        fdr[12]=f1.x; fdr[13]=f1.y; fdr[14]=f1.z; fdr[15]=f1.w;
        avr[8]=a0.x; avr[9]=a0.y; avr[10]=a0.z; avr[11]=a0.w;
        avr[12]=a1.x; avr[13]=a1.y; avr[14]=a1.z; avr[15]=a1.w;
    }
    __syncthreads();

    for (int k = wave; k < KTOP; k += 4) {
        const ushort_t* g = fsrc_bf + ((size_t)(b << 9) + kid[k]) * D;
        float s = 0.f;
        const bf16x8 g0 = *(const bf16x8*)(g + lane * 8);
#pragma unroll
        for (int jj = 0; jj < 8; ++jj) {
            float x = (float)g0[jj] + fdr[jj];
            x = x > 0.f ? x : 0.2f * x;
            s += x * avr[jj];
        }
        if (lane < 32) {
            const bf16x8 g1 = *(const bf16x8*)(g + (lane + 64) * 8);
#pragma unroll
            for (int jj = 0; jj < 8; ++jj) {
                float x = (float)g1[jj] + fdr[8 + jj];
                x = x > 0.f ? x : 0.2f * x;
                s += x * avr[8 + jj];
            }
        }
#pragma unroll
        for (int off = 32; off > 0; off >>= 1) s += __shfl_down(s, off);
        if (lane == 0) sc[k] = (kvv[k] > 0.f) ? s : -1e9f;
    }
    __syncthreads();

    // softmax over KTOP (wave 0)
    if (wave == 0) {
        float s = (lane < KTOP) ? sc[lane] : -3.0e38f;
        float m = s;
#pragma unroll
        for (int off = 32; off > 0; off >>= 1) m = fmaxf(m, __shfl_xor(m, off));
        float e = (lane < KTOP) ? __expf(s - m) : 0.f;
        float sum = e;
#pragma unroll
        for (int off = 32; off > 0; off >>= 1) sum += __shfl_xor(sum, off);
        if (lane < KTOP) sc[lane] = e / sum;
    }
    __syncthreads();

    // scatter probs into P (indices within a row are distinct)
    if (tid < KTOP)
        P[(size_t)row * LSEQ + kid[tid]] = f2bf(sc[tid]);
}

// ---------------------------------------------------------------------------
// P-GEMM + fused resgate, 64x64 tiles: h' = P@fsrc + gat_bias;
// h = leaky(h' + hidden, 0.01) stored as BF16; gate partials via
// shuffle+atomicAdd (gate seeded with gate_b in score).
// ---------------------------------------------------------------------------
__global__ __launch_bounds__(256) void pgemm_kernel(const ushort_t* __restrict__ P,
                                                    const ushort_t* __restrict__ fsrcT,
                                                    const float* __restrict__ gat_bias,
                                                    const float* __restrict__ hidden,
                                                    const float* __restrict__ gate_W,
                                                    ushort_t* __restrict__ h,
                                                    float* __restrict__ gate) {
    const int bb = blockIdx.z;
    const ushort_t* Ab = P + (size_t)bb * LSEQ * LSEQ;
    const ushort_t* Bb = fsrcT + (size_t)bb * D * LSEQ;

    __shared__ ushort_t As[64 * 32];
    __shared__ ushort_t Bs[64 * 32];

    const int tid = threadIdx.x;
    const int lane = tid & 63;
    const int wave = tid >> 6;
    const int quad = lane >> 4;
    const int m15 = lane & 15;
    const int qRow = (wave & 1) * 32;
    const int qCol = (wave >> 1) * 32;

    const int rowBase = blockIdx.y * 64;    // over L=512
    const int colBase = blockIdx.x * 64;    // over D=768

    const int e0 = tid * 8;
    const int r0 = e0 >> 5;
    const int c0 = e0 & 31;
    const ushort_t* Abase = Ab + (size_t)rowBase * LSEQ;
    const ushort_t* Bbase = Bb + (size_t)colBase * LSEQ;

    f32x4 acc[2][2] = {};

    for (int kk = 0; kk < LSEQ; kk += 32) {
        __syncthreads();
        GLOAD16(Abase + (size_t)r0 * LSEQ + kk + c0, &As[e0]);
        GLOAD16(Bbase + (size_t)r0 * LSEQ + kk + c0, &Bs[e0]);
        __syncthreads();

        bf16x8 a[2], b[2];
#pragma unroll
        for (int i = 0; i < 2; ++i)
            a[i] = *(const bf16x8*)&As[(qRow + i * 16 + m15) * 32 + quad * 8];
#pragma unroll
        for (int j = 0; j < 2; ++j)
            b[j] = *(const bf16x8*)&Bs[(qCol + j * 16 + m15) * 32 + quad * 8];
#pragma unroll
        for (int i = 0; i < 2; ++i)
#pragma unroll
            for (int j = 0; j < 2; ++j)
                acc[i][j] = __builtin_amdgcn_mfma_f32_16x16x32_bf16(a[i], b[j], acc[i][j], 0, 0, 0);
    }

    // epilogue: residual + leaky + store h (bf16) + gate partial dot
    const float* hidb = hidden + (size_t)bb * LSEQ * D;
    ushort_t* hb = h + (size_t)bb * LSEQ * D;
    float rp[2][4] = {};    // [i][r] per-row gate partials
#pragma unroll
    for (int j = 0; j < 2; ++j) {
        const int col = colBase + qCol + j * 16 + m15;
        const float bv = gat_bias[col];
        const float gw = gate_W[col];
#pragma unroll
        for (int i = 0; i < 2; ++i) {
            const int row0 = rowBase + qRow + i * 16 + quad * 4;
#pragma unroll
            for (int r = 0; r < 4; ++r) {
                float v = acc[i][j][r] + bv + hidb[(size_t)(row0 + r) * D + col];
                v = v > 0.f ? v : 0.01f * v;
                hb[(size_t)(row0 + r) * D + col] = f2bf(v);
                rp[i][r] += v * gw;
            }
        }
    }
#pragma unroll
    for (int i = 0; i < 2; ++i)
#pragma unroll
        for (int r = 0; r < 4; ++r) {
            float p4 = rp[i][r];
            p4 += __shfl_xor(p4, 1);
            p4 += __shfl_xor(p4, 2);
            p4 += __shfl_xor(p4, 4);
            p4 += __shfl_xor(p4, 8);
            if (m15 == 0)
                atomicAdd(&gate[bb * LSEQ + rowBase + qRow + i * 16 + quad * 4 + r], p4);
        }
}

// ---------------------------------------------------------------------------
// pool (gate-softmax fused): each block recomputes the per-batch softmax
// stats over gate (512 values, cheap) then accumulates its 64-l chunk of
// pooled[b][d] = sum_l p[b][l]*h[b][l][d]. h is bf16.
// ---------------------------------------------------------------------------
__global__ __launch_bounds__(256) void pool_kernel(const ushort_t* __restrict__ h,
                                                   const float* __restrict__ gate,
                                                   float* __restrict__ pooled) {
    const int b = blockIdx.z;
    const int lbase = blockIdx.y * 64;
    const int d = blockIdx.x * 256 + threadIdx.x;
    const int tid = threadIdx.x;

    __shared__ float red[256];
    __shared__ float ps[64];

    const float g0 = gate[b * LSEQ + tid];
    const float g1 = gate[b * LSEQ + tid + 256];
    red[tid] = fmaxf(g0, g1);
    __syncthreads();
    for (int s = 128; s > 0; s >>= 1) { if (tid < s) red[tid] = fmaxf(red[tid], red[tid + s]); __syncthreads(); }
    const float m = red[0];
    __syncthreads();
    red[tid] = __expf(g0 - m) + __expf(g1 - m);
    __syncthreads();
    for (int s = 128; s > 0; s >>= 1) { if (tid < s) red[tid] += red[tid + s]; __syncthreads(); }
    const float inv = 1.f / red[0];
    if (tid < 64) ps[tid] = __expf(gate[b * LSEQ + lbase + tid] - m) * inv;
    __syncthreads();

    const ushort_t* hb = h + ((size_t)(b * LSEQ + lbase)) * D + d;
    float acc = 0.f;
#pragma unroll 8
    for (int l = 0; l < 64; ++l) {
        acc += ps[l] * bf2f(hb[(size_t)l * D]);
    }
    atomicAdd(&pooled[b * D + d], acc);
}

// ---------------------------------------------------------------------------
// fc (LN1 + LN2 fused): each block recomputes relu+LN(768) stats from pooled,
// normalizes its 256-d chunk into LDS, accumulates partial z via atomicAdd.
// The LAST block (device-scope completion counter == 71) then performs ln2
// for all batches, reading z via device-scope atomic loads (coherent across
// XCDs) — saves the separate ln2 dispatch.
// ---------------------------------------------------------------------------
__global__ __launch_bounds__(256) void fc_kernel(const float* __restrict__ pooled,
                                                 const float* __restrict__ ln_g,
                                                 const float* __restrict__ ln_b,
                                                 const float* __restrict__ fc_W,
                                                 float* __restrict__ z,
                                                 const float* __restrict__ fc_b,
                                                 const float* __restrict__ ln2_g,
                                                 const float* __restrict__ ln2_b,
                                                 float* __restrict__ out,
                                                 int* __restrict__ fcnt) {
    const int b = blockIdx.z;
    const int by = blockIdx.y;          // 0..2, which 256-d chunk
    const int dbase = by * 256;
    const int jbase = blockIdx.x * 64;
    const int tid = threadIdx.x;
    const int jt = tid & 63;
    const int sub = tid >> 6;

    __shared__ float red[256];
    __shared__ float ys[256];
    __shared__ float part[4][64];
    __shared__ int lastFlag;

    float v[3];
#pragma unroll
    for (int i = 0; i < 3; ++i) v[i] = fmaxf(pooled[b * D + tid + i * 256], 0.f);

    red[tid] = v[0] + v[1] + v[2];
    __syncthreads();
    for (int s = 128; s > 0; s >>= 1) { if (tid < s) red[tid] += red[tid + s]; __syncthreads(); }
    const float mu = red[0] / (float)D;
    __syncthreads();
    float vs = 0.f;
#pragma unroll
    for (int i = 0; i < 3; ++i) { const float dd = v[i] - mu; vs += dd * dd; }
    red[tid] = vs;
    __syncthreads();
    for (int s = 128; s > 0; s >>= 1) { if (tid < s) red[tid] += red[tid + s]; __syncthreads(); }
    const float rstd = rsqrtf(red[0] / (float)D + EPS);

    const float vb = (by == 0) ? v[0] : (by == 1 ? v[1] : v[2]);
    ys[tid] = (vb - mu) * rstd * ln_g[dbase + tid] + ln_b[dbase + tid];
    __syncthreads();

    const float* W = fc_W + (size_t)(dbase + sub * 64) * DOUT + jbase + jt;
    const float* yy = ys + sub * 64;
    float acc = 0.f;
#pragma unroll 8
    for (int i = 0; i < 64; ++i) {
        acc += yy[i] * W[(size_t)i * DOUT];
    }
    part[sub][jt] = acc;
    __syncthreads();
    if (sub == 0) {
        const float tot = part[0][jt] + part[1][jt] + part[2][jt] + part[3][jt];
        atomicAdd(&z[b * DOUT + jbase + jt], tot);
    }
    // completion protocol: drain this block's z-atomics, then bump counter.
    __syncthreads();
    if (tid == 0) {
        __threadfence();
        const int old = atomicAdd(fcnt, 1);
        lastFlag = (old == (DOUT / 64) * (D / 256) * BATCH - 1);   // 71
    }
    __syncthreads();
    if (!lastFlag) return;

    // ----- last block: LN(384) + write out, all batches -----
    for (int bb = 0; bb < BATCH; ++bb) {
        const float z0 = atomicAdd(&z[bb * DOUT + tid], 0.f) + fc_b[tid];
        const float z1 = (tid < 128)
            ? atomicAdd(&z[bb * DOUT + 256 + tid], 0.f) + fc_b[256 + tid] : 0.f;
        red[tid] = z0 + z1;
        __syncthreads();
        for (int s = 128; s > 0; s >>= 1) { if (tid < s) red[tid] += red[tid + s]; __syncthreads(); }
        const float mu2 = red[0] / (float)DOUT;
        __syncthreads();
        const float d0 = z0 - mu2;
        const float d1 = (tid < 128) ? (z1 - mu2) : 0.f;
        red[tid] = d0 * d0 + d1 * d1;
        __syncthreads();
        for (int s = 128; s > 0; s >>= 1) { if (tid < s) red[tid] += red[tid + s]; __syncthreads(); }
        const float rstd2 = rsqrtf(red[0] / (float)DOUT + EPS);
        __syncthreads();
        out[bb * DOUT + tid] = d0 * rstd2 * ln2_g[tid] + ln2_b[tid];
        if (tid < 128)
            out[bb * DOUT + 256 + tid] = d1 * rstd2 * ln2_g[256 + tid] + ln2_b[256 + tid];
        __syncthreads();
    }
}

extern "C" void kernel_launch(void* const* d_in, const int* in_sizes, int n_in,
                              void* d_out, int out_size, void* d_ws, size_t ws_size,
                              hipStream_t stream) {
    const float* hidden   = (const float*)d_in[0];   // (4,512,768)
    const float* attention= (const float*)d_in[1];   // (4,512,512)
    const float* W_src    = (const float*)d_in[2];
    const float* b_src    = (const float*)d_in[3];
    const float* W_dst    = (const float*)d_in[4];
    const float* b_dst    = (const float*)d_in[5];
    const float* attn_vec = (const float*)d_in[6];
    const float* gat_bias = (const float*)d_in[7];
    const float* gate_W   = (const float*)d_in[8];
    const float* gate_b   = (const float*)d_in[9];
    const float* ln_g     = (const float*)d_in[10];
    const float* ln_b     = (const float*)d_in[11];
    const float* fc_W     = (const float*)d_in[12];
    const float* fc_b     = (const float*)d_in[13];
    const float* ln2_g    = (const float*)d_in[14];
    const float* ln2_b    = (const float*)d_in[15];
    float* out = (float*)d_out;

    const int M = BATCH * LSEQ;           // 2048
    float* feat_dst = (float*)d_ws;                       // M*D fp32
    float* gate     = feat_dst + (size_t)M * D;           // M
    float* pooled   = gate + M;                           // B*D
    float* z        = pooled + BATCH * D;                 // B*DOUT
    int*   fcnt     = (int*)(z + BATCH * DOUT);           // 1 (pad to 8)
    ushort_t* Ah    = (ushort_t*)(fcnt + 8);              // M*D bf16
    ushort_t* WT0   = Ah + (size_t)M * D;                 // D*D bf16 [n][k]
    ushort_t* WT1   = WT0 + (size_t)D * D;                // D*D bf16 [n][k]
    ushort_t* fsrcb = WT1 + (size_t)D * D;                // M*D bf16
    ushort_t* fsrcT = fsrcb + (size_t)M * D;              // M*D bf16 (batch 768x512)
    ushort_t* P     = fsrcT + (size_t)M * D;              // M*LSEQ bf16
    ushort_t* h     = P + (size_t)M * LSEQ;               // M*D bf16

    hipLaunchKernelGGL(prep_kernel, dim3(2689), dim3(256), 0, stream,
                       hidden, Ah, W_src, W_dst, WT0, WT1, pooled, z, fcnt);
    hipLaunchKernelGGL(feat_gemm_kernel, dim3(D / 64, M / 64, 2), dim3(256), 0, stream,
                       Ah, WT0, b_src, fsrcb, WT1, b_dst, feat_dst);
    hipLaunchKernelGGL(score_kernel, dim3(1536 + M), dim3(256), 0, stream,
                       attention, fsrcb, fsrcT, feat_dst, attn_vec, gate_b, P, gate);
    hipLaunchKernelGGL(pgemm_kernel, dim3(D / 64, LSEQ / 64, BATCH), dim3(256), 0, stream,
                       P, fsrcT, gat_bias, hidden, gate_W, h, gate);
    hipLaunchKernelGGL(pool_kernel, dim3(D / 256, LSEQ / 64, BATCH), dim3(256), 0, stream,
                       h, gate, pooled);
    hipLaunchKernelGGL(fc_kernel, dim3(DOUT / 64, D / 256, BATCH), dim3(256), 0, stream,
                       pooled, ln_g, ln_b, fc_W, z, fc_b, ln2_g, ln2_b, out, fcnt);
}

// Round 12
// 176.475 us; speedup vs baseline: 1.0707x; 1.0707x over previous
//
#include <hip/hip_runtime.h>
#include <math.h>

#define D 768
#define DOUT 384
#define LSEQ 512
#define BATCH 4
#define KTOP 51
#define EPS 1e-5f

typedef unsigned short ushort_t;
typedef __bf16 bf16x8 __attribute__((ext_vector_type(8)));
typedef float f32x4 __attribute__((ext_vector_type(4)));

// global->LDS direct DMA, 16B per lane. LDS dest is wave-uniform base + lane*16.
#define GLOAD16(gp, lp)                                                        \
    __builtin_amdgcn_global_load_lds(                                          \
        (const __attribute__((address_space(1))) unsigned int*)(gp),           \
        (__attribute__((address_space(3))) unsigned int*)(lp), 16, 0, 0)

// fp32 -> bf16 round-to-nearest-even (inputs are finite; NaN path not needed)
__device__ __forceinline__ ushort_t f2bf(float f) {
    unsigned int u = __builtin_bit_cast(unsigned int, f);
    u = (u + 0x7FFFu + ((u >> 16) & 1u)) >> 16;
    return (ushort_t)u;
}

__device__ __forceinline__ float bf2f(ushort_t u) {
    unsigned int v = ((unsigned int)u) << 16;
    return __builtin_bit_cast(float, v);
}

// ---------------------------------------------------------------------------
// Prep: blocks [0,1536) convert hidden fp32->bf16; blocks [1536,2688) do the
// two 768x768 W transposes; block 2688 zeroes pooled/z accumulators.
// ---------------------------------------------------------------------------
__global__ __launch_bounds__(256) void prep_kernel(const float* __restrict__ hidden,
                                                   ushort_t* __restrict__ Ah,
                                                   const float* __restrict__ W0,
                                                   const float* __restrict__ W1,
                                                   ushort_t* __restrict__ WT0,
                                                   ushort_t* __restrict__ WT1,
                                                   float* __restrict__ pooled,
                                                   float* __restrict__ z) {
    __shared__ float tile[32][33];
    const int bid = blockIdx.x;
    const int tid = threadIdx.x;
    if (bid < 1536) {
        const int i = (bid * 256 + tid) * 4;
        const float4 v = *(const float4*)(hidden + i);
        ushort4 o;
        o.x = f2bf(v.x); o.y = f2bf(v.y); o.z = f2bf(v.z); o.w = f2bf(v.w);
        *(ushort4*)(Ah + i) = o;
    } else if (bid < 2688) {
        const int t = bid - 1536;
        const int zz = t / 576;
        const int rem = t - zz * 576;
        const int by = rem / 24, bx = rem - by * 24;
        const float* W = zz ? W1 : W0;
        ushort_t* WT = zz ? WT1 : WT0;
        const int kbase = by * 32;
        const int nbase = bx * 32;
        const int r = tid >> 3, c4 = (tid & 7) * 4;

        const float4 v = *(const float4*)(W + (size_t)(kbase + r) * D + nbase + c4);
        tile[r][c4 + 0] = v.x; tile[r][c4 + 1] = v.y;
        tile[r][c4 + 2] = v.z; tile[r][c4 + 3] = v.w;
        __syncthreads();
        ushort4 o;
        o.x = f2bf(tile[c4 + 0][r]); o.y = f2bf(tile[c4 + 1][r]);
        o.z = f2bf(tile[c4 + 2][r]); o.w = f2bf(tile[c4 + 3][r]);
        *(ushort4*)(WT + (size_t)(nbase + r) * D + kbase + c4) = o;
    } else {
        for (int i = tid; i < BATCH * D; i += 256) pooled[i] = 0.f;
        for (int i = tid; i < BATCH * DOUT; i += 256) z[i] = 0.f;
    }
}

// ---------------------------------------------------------------------------
// Feature GEMM (bf16 MFMA): A(2048x768) @ W(768x768) + bias.
// 64x64 tiles (wave = 32x32 quadrant, 2x2 frags): 768 blocks = 3 blocks/CU.
// z==0: W_src -> fsrc_bf (bf16). z==1: W_dst -> feat_dst (fp32).
// ---------------------------------------------------------------------------
__global__ __launch_bounds__(256) void feat_gemm_kernel(const ushort_t* __restrict__ Ah,
                                                        const ushort_t* __restrict__ WT0,
                                                        const float* __restrict__ b0,
                                                        ushort_t* __restrict__ Csrc_bf,
                                                        const ushort_t* __restrict__ WT1,
                                                        const float* __restrict__ b1,
                                                        float* __restrict__ Cdst) {
    const ushort_t* WT = blockIdx.z ? WT1 : WT0;
    const float* bias = blockIdx.z ? b1 : b0;

    __shared__ ushort_t As[64 * 32];
    __shared__ ushort_t Bs[64 * 32];

    const int tid = threadIdx.x;
    const int lane = tid & 63;
    const int wave = tid >> 6;
    const int quad = lane >> 4;
    const int m15 = lane & 15;
    const int qRow = (wave & 1) * 32;
    const int qCol = (wave >> 1) * 32;

    const int rowBase = blockIdx.y * 64;
    const int colBase = blockIdx.x * 64;

    const int e0 = tid * 8;          // covers 64*32 = 2048 elems
    const int r0 = e0 >> 5;
    const int c0 = e0 & 31;
    const ushort_t* Abase = Ah + (size_t)rowBase * D;
    const ushort_t* Bbase = WT + (size_t)colBase * D;

    f32x4 acc[2][2] = {};

    for (int kk = 0; kk < D; kk += 32) {
        __syncthreads();
        GLOAD16(Abase + (size_t)r0 * D + kk + c0, &As[e0]);
        GLOAD16(Bbase + (size_t)r0 * D + kk + c0, &Bs[e0]);
        __syncthreads();

        bf16x8 a[2], b[2];
#pragma unroll
        for (int i = 0; i < 2; ++i)
            a[i] = *(const bf16x8*)&As[(qRow + i * 16 + m15) * 32 + quad * 8];
#pragma unroll
        for (int j = 0; j < 2; ++j)
            b[j] = *(const bf16x8*)&Bs[(qCol + j * 16 + m15) * 32 + quad * 8];
#pragma unroll
        for (int i = 0; i < 2; ++i)
#pragma unroll
            for (int j = 0; j < 2; ++j)
                acc[i][j] = __builtin_amdgcn_mfma_f32_16x16x32_bf16(a[i], b[j], acc[i][j], 0, 0, 0);
    }

    // C/D layout: col=lane&15, row=quad*4+reg
    if (blockIdx.z == 0) {
#pragma unroll
        for (int j = 0; j < 2; ++j) {
            const int col = colBase + qCol + j * 16 + m15;
            const float bv = bias[col];
#pragma unroll
            for (int i = 0; i < 2; ++i) {
                ushort_t* Cp = Csrc_bf + (size_t)(rowBase + qRow + i * 16 + quad * 4) * D + col;
#pragma unroll
                for (int r = 0; r < 4; ++r)
                    Cp[(size_t)r * D] = f2bf(acc[i][j][r] + bv);
            }
        }
    } else {
#pragma unroll
        for (int j = 0; j < 2; ++j) {
            const int col = colBase + qCol + j * 16 + m15;
            const float bv = bias[col];
#pragma unroll
            for (int i = 0; i < 2; ++i) {
                float* Cp = Cdst + (size_t)(rowBase + qRow + i * 16 + quad * 4) * D + col;
#pragma unroll
                for (int r = 0; r < 4; ++r)
                    Cp[(size_t)r * D] = acc[i][j][r] + bv;
            }
        }
    }
}

// ---------------------------------------------------------------------------
// Transpose fsrc_bf per batch: (512x768) -> fsrcT (768x512), bf16 32x32 tiles.
// ---------------------------------------------------------------------------
__global__ __launch_bounds__(256) void transpose_fsrc_kernel(const ushort_t* __restrict__ I,
                                                             ushort_t* __restrict__ O) {
    __shared__ ushort_t tile[32][33];
    const int b = blockIdx.z;
    const int cbase = blockIdx.x * 32;   // over D=768
    const int rbase = blockIdx.y * 32;   // over L=512
    const int tid = threadIdx.x;
    const int tr = tid >> 3, tc4 = (tid & 7) * 4;

    const ushort_t* Ib = I + (size_t)b * LSEQ * D;
    ushort_t* Ob = O + (size_t)b * D * LSEQ;

    const ushort4 v = *(const ushort4*)(Ib + (size_t)(rbase + tr) * D + cbase + tc4);
    tile[tr][tc4 + 0] = v.x; tile[tr][tc4 + 1] = v.y;
    tile[tr][tc4 + 2] = v.z; tile[tr][tc4 + 3] = v.w;
    __syncthreads();
    ushort4 o;
    o.x = tile[tc4 + 0][tr]; o.y = tile[tc4 + 1][tr];
    o.z = tile[tc4 + 2][tr]; o.w = tile[tc4 + 3][tr];
    *(ushort4*)(Ob + (size_t)(cbase + tr) * LSEQ + rbase + tc4) = o;
}

// ---------------------------------------------------------------------------
// Score kernel (topk fused): statistical pre-filter top-51 + exact-rank
// fallback; gather-dot-leaky scores; softmax; scatter bf16 probs into P;
// seed gate[row] = gate_b.
// ---------------------------------------------------------------------------
__global__ __launch_bounds__(256) void score_kernel(const float* __restrict__ attn,
                                                    const ushort_t* __restrict__ fsrc_bf,
                                                    const float* __restrict__ feat_dst,
                                                    const float* __restrict__ attn_vec,
                                                    const float* __restrict__ gate_b,
                                                    ushort_t* __restrict__ P,
                                                    float* __restrict__ gate) {
    const int row = blockIdx.x;     // b*L + l
    const int b = row >> 9;
    const int tid = threadIdx.x;
    const int lane = tid & 63;
    const int wave = tid >> 6;

    __shared__ float vals[LSEQ];
    __shared__ float cval[320];
    __shared__ int   cidx[320];
    __shared__ int   nhi, outSlot;
    __shared__ float sc[KTOP];
    __shared__ int   kid[KTOP];
    __shared__ float kvv[KTOP];

    // zero this row of P; seed gate accumulator with bias
    ((unsigned int*)(P + (size_t)row * LSEQ))[tid] = 0u;
    if (tid == 0) { gate[row] = gate_b[0]; nhi = 0; outSlot = 0; }

    const float* a = attn + (size_t)row * LSEQ;
    const float v0 = a[tid];
    const float v1 = a[tid + 256];
    vals[tid] = v0;
    vals[tid + 256] = v1;
    __syncthreads();

    if (v0 > 0.75f) {
        const int s = atomicAdd(&nhi, 1);
        if (s < 320) { cval[s] = v0; cidx[s] = tid; }
    }
    if (v1 > 0.75f) {
        const int s = atomicAdd(&nhi, 1);
        if (s < 320) { cval[s] = v1; cidx[s] = tid + 256; }
    }
    __syncthreads();

    const int n = nhi;
    if (n >= KTOP && n <= 320) {
        // fast path: rank within survivor set == global rank for survivors
        if (tid < n) {
            const float v = cval[tid];
            const int e = cidx[tid];
            int r = 0;
            for (int j = 0; j < n; ++j) {
                const float u = cval[j];
                r += (u > v) || (u == v && cidx[j] < e);
            }
            if (r < KTOP) {
                const int s = atomicAdd(&outSlot, 1);
                kid[s] = e; kvv[s] = v;
            }
        }
    } else {
        // exact fallback for arbitrary inputs
#pragma unroll
        for (int e0 = 0; e0 < 2; ++e0) {
            const int e = tid + e0 * 256;
            const float v = vals[e];
            int r = 0;
            for (int j = 0; j < LSEQ; ++j) {
                const float u = vals[j];
                r += (u > v) || (u == v && j < e);
            }
            if (r < KTOP) {
                const int s = atomicAdd(&outSlot, 1);
                kid[s] = e; kvv[s] = v;
            }
        }
    }

    // per-lane register slices: chunk c=lane (all lanes), c=lane+64 (lanes<32)
    const float* fdp = feat_dst + (size_t)row * D;
    float fdr[16], avr[16];
    {
        const int d0 = lane * 8;
        const float4 f0 = *(const float4*)(fdp + d0);
        const float4 f1 = *(const float4*)(fdp + d0 + 4);
        const float4 a0 = *(const float4*)(attn_vec + d0);
        const float4 a1 = *(const float4*)(attn_vec + d0 + 4);
        fdr[0]=f0.x; fdr[1]=f0.y; fdr[2]=f0.z; fdr[3]=f0.w;
        fdr[4]=f1.x; fdr[5]=f1.y; fdr[6]=f1.z; fdr[7]=f1.w;
        avr[0]=a0.x; avr[1]=a0.y; avr[2]=a0.z; avr[3]=a0.w;
        avr[4]=a1.x; avr[5]=a1.y; avr[6]=a1.z; avr[7]=a1.w;
    }
    if (lane < 32) {
        const int d1 = (lane + 64) * 8;
        const float4 f0 = *(const float4*)(fdp + d1);
        const float4 f1 = *(const float4*)(fdp + d1 + 4);
        const float4 a0 = *(const float4*)(attn_vec + d1);
        const float4 a1 = *(const float4*)(attn_vec + d1 + 4);
        fdr[8]=f0.x; fdr[9]=f0.y; fdr[10]=f0.z; fdr[11]=f0.w;
        fdr[12]=f1.x; fdr[13]=f1.y; fdr[14]=f1.z; fdr[15]=f1.w;
        avr[8]=a0.x; avr[9]=a0.y; avr[10]=a0.z; avr[11]=a0.w;
        avr[12]=a1.x; avr[13]=a1.y; avr[14]=a1.z; avr[15]=a1.w;
    }
    __syncthreads();

    for (int k = wave; k < KTOP; k += 4) {
        const ushort_t* g = fsrc_bf + ((size_t)(b << 9) + kid[k]) * D;
        float s = 0.f;
        const bf16x8 g0 = *(const bf16x8*)(g + lane * 8);
#pragma unroll
        for (int jj = 0; jj < 8; ++jj) {
            float x = (float)g0[jj] + fdr[jj];
            x = x > 0.f ? x : 0.2f * x;
            s += x * avr[jj];
        }
        if (lane < 32) {
            const bf16x8 g1 = *(const bf16x8*)(g + (lane + 64) * 8);
#pragma unroll
            for (int jj = 0; jj < 8; ++jj) {
                float x = (float)g1[jj] + fdr[8 + jj];
                x = x > 0.f ? x : 0.2f * x;
                s += x * avr[8 + jj];
            }
        }
#pragma unroll
        for (int off = 32; off > 0; off >>= 1) s += __shfl_down(s, off);
        if (lane == 0) sc[k] = (kvv[k] > 0.f) ? s : -1e9f;
    }
    __syncthreads();

    // softmax over KTOP (wave 0)
    if (wave == 0) {
        float s = (lane < KTOP) ? sc[lane] : -3.0e38f;
        float m = s;
#pragma unroll
        for (int off = 32; off > 0; off >>= 1) m = fmaxf(m, __shfl_xor(m, off));
        float e = (lane < KTOP) ? __expf(s - m) : 0.f;
        float sum = e;
#pragma unroll
        for (int off = 32; off > 0; off >>= 1) sum += __shfl_xor(sum, off);
        if (lane < KTOP) sc[lane] = e / sum;
    }
    __syncthreads();

    // scatter probs into P (indices within a row are distinct)
    if (tid < KTOP)
        P[(size_t)row * LSEQ + kid[tid]] = f2bf(sc[tid]);
}

// ---------------------------------------------------------------------------
// P-GEMM + fused resgate, 64x64 tiles: h' = P@fsrc + gat_bias;
// h = leaky(h' + hidden, 0.01) stored as BF16 (halves pool's read traffic;
// gate dot uses fp32 v pre-conversion); gate partials via shuffle+atomicAdd.
// ---------------------------------------------------------------------------
__global__ __launch_bounds__(256) void pgemm_kernel(const ushort_t* __restrict__ P,
                                                    const ushort_t* __restrict__ fsrcT,
                                                    const float* __restrict__ gat_bias,
                                                    const float* __restrict__ hidden,
                                                    const float* __restrict__ gate_W,
                                                    ushort_t* __restrict__ h,
                                                    float* __restrict__ gate) {
    const int bb = blockIdx.z;
    const ushort_t* Ab = P + (size_t)bb * LSEQ * LSEQ;
    const ushort_t* Bb = fsrcT + (size_t)bb * D * LSEQ;

    __shared__ ushort_t As[64 * 32];
    __shared__ ushort_t Bs[64 * 32];

    const int tid = threadIdx.x;
    const int lane = tid & 63;
    const int wave = tid >> 6;
    const int quad = lane >> 4;
    const int m15 = lane & 15;
    const int qRow = (wave & 1) * 32;
    const int qCol = (wave >> 1) * 32;

    const int rowBase = blockIdx.y * 64;    // over L=512
    const int colBase = blockIdx.x * 64;    // over D=768

    const int e0 = tid * 8;
    const int r0 = e0 >> 5;
    const int c0 = e0 & 31;
    const ushort_t* Abase = Ab + (size_t)rowBase * LSEQ;
    const ushort_t* Bbase = Bb + (size_t)colBase * LSEQ;

    f32x4 acc[2][2] = {};

    for (int kk = 0; kk < LSEQ; kk += 32) {
        __syncthreads();
        GLOAD16(Abase + (size_t)r0 * LSEQ + kk + c0, &As[e0]);
        GLOAD16(Bbase + (size_t)r0 * LSEQ + kk + c0, &Bs[e0]);
        __syncthreads();

        bf16x8 a[2], b[2];
#pragma unroll
        for (int i = 0; i < 2; ++i)
            a[i] = *(const bf16x8*)&As[(qRow + i * 16 + m15) * 32 + quad * 8];
#pragma unroll
        for (int j = 0; j < 2; ++j)
            b[j] = *(const bf16x8*)&Bs[(qCol + j * 16 + m15) * 32 + quad * 8];
#pragma unroll
        for (int i = 0; i < 2; ++i)
#pragma unroll
            for (int j = 0; j < 2; ++j)
                acc[i][j] = __builtin_amdgcn_mfma_f32_16x16x32_bf16(a[i], b[j], acc[i][j], 0, 0, 0);
    }

    // epilogue: residual + leaky + store h (bf16) + gate partial dot
    const float* hidb = hidden + (size_t)bb * LSEQ * D;
    ushort_t* hb = h + (size_t)bb * LSEQ * D;
    float rp[2][4] = {};    // [i][r] per-row gate partials
#pragma unroll
    for (int j = 0; j < 2; ++j) {
        const int col = colBase + qCol + j * 16 + m15;
        const float bv = gat_bias[col];
        const float gw = gate_W[col];
#pragma unroll
        for (int i = 0; i < 2; ++i) {
            const int row0 = rowBase + qRow + i * 16 + quad * 4;
#pragma unroll
            for (int r = 0; r < 4; ++r) {
                float v = acc[i][j][r] + bv + hidb[(size_t)(row0 + r) * D + col];
                v = v > 0.f ? v : 0.01f * v;
                hb[(size_t)(row0 + r) * D + col] = f2bf(v);
                rp[i][r] += v * gw;
            }
        }
    }
#pragma unroll
    for (int i = 0; i < 2; ++i)
#pragma unroll
        for (int r = 0; r < 4; ++r) {
            float p4 = rp[i][r];
            p4 += __shfl_xor(p4, 1);
            p4 += __shfl_xor(p4, 2);
            p4 += __shfl_xor(p4, 4);
            p4 += __shfl_xor(p4, 8);
            if (m15 == 0)
                atomicAdd(&gate[bb * LSEQ + rowBase + qRow + i * 16 + quad * 4 + r], p4);
        }
}

// ---------------------------------------------------------------------------
// pool (gate-softmax fused): each block recomputes the per-batch softmax
// stats over gate (512 values, cheap) then accumulates its 64-l chunk of
// pooled[b][d] = sum_l p[b][l]*h[b][l][d]. h is bf16.
// ---------------------------------------------------------------------------
__global__ __launch_bounds__(256) void pool_kernel(const ushort_t* __restrict__ h,
                                                   const float* __restrict__ gate,
                                                   float* __restrict__ pooled) {
    const int b = blockIdx.z;
    const int lbase = blockIdx.y * 64;
    const int d = blockIdx.x * 256 + threadIdx.x;
    const int tid = threadIdx.x;

    __shared__ float red[256];
    __shared__ float ps[64];

    const float g0 = gate[b * LSEQ + tid];
    const float g1 = gate[b * LSEQ + tid + 256];
    red[tid] = fmaxf(g0, g1);
    __syncthreads();
    for (int s = 128; s > 0; s >>= 1) { if (tid < s) red[tid] = fmaxf(red[tid], red[tid + s]); __syncthreads(); }
    const float m = red[0];
    __syncthreads();
    red[tid] = __expf(g0 - m) + __expf(g1 - m);
    __syncthreads();
    for (int s = 128; s > 0; s >>= 1) { if (tid < s) red[tid] += red[tid + s]; __syncthreads(); }
    const float inv = 1.f / red[0];
    if (tid < 64) ps[tid] = __expf(gate[b * LSEQ + lbase + tid] - m) * inv;
    __syncthreads();

    const ushort_t* hb = h + ((size_t)(b * LSEQ + lbase)) * D + d;
    float acc = 0.f;
#pragma unroll 8
    for (int l = 0; l < 64; ++l) {
        acc += ps[l] * bf2f(hb[(size_t)l * D]);
    }
    atomicAdd(&pooled[b * D + d], acc);
}

// ---------------------------------------------------------------------------
// fc (LN1 fused): each block recomputes relu+LN(768) stats from pooled
// (3 floats/thread + 2 reductions, cheap), normalizes its 256-d chunk into
// LDS, then partial z[b][j] += sum_d ys[d]*fc_W[d][j].  72 blocks.
// ---------------------------------------------------------------------------
__global__ __launch_bounds__(256) void fc_kernel(const float* __restrict__ pooled,
                                                 const float* __restrict__ ln_g,
                                                 const float* __restrict__ ln_b,
                                                 const float* __restrict__ fc_W,
                                                 float* __restrict__ z) {
    const int b = blockIdx.z;
    const int by = blockIdx.y;          // 0..2, which 256-d chunk
    const int dbase = by * 256;
    const int jbase = blockIdx.x * 64;
    const int tid = threadIdx.x;
    const int jt = tid & 63;
    const int sub = tid >> 6;

    __shared__ float red[256];
    __shared__ float ys[256];
    __shared__ float part[4][64];

    float v[3];
#pragma unroll
    for (int i = 0; i < 3; ++i) v[i] = fmaxf(pooled[b * D + tid + i * 256], 0.f);

    red[tid] = v[0] + v[1] + v[2];
    __syncthreads();
    for (int s = 128; s > 0; s >>= 1) { if (tid < s) red[tid] += red[tid + s]; __syncthreads(); }
    const float mu = red[0] / (float)D;
    __syncthreads();
    float vs = 0.f;
#pragma unroll
    for (int i = 0; i < 3; ++i) { const float dd = v[i] - mu; vs += dd * dd; }
    red[tid] = vs;
    __syncthreads();
    for (int s = 128; s > 0; s >>= 1) { if (tid < s) red[tid] += red[tid + s]; __syncthreads(); }
    const float rstd = rsqrtf(red[0] / (float)D + EPS);

    const float vb = (by == 0) ? v[0] : (by == 1 ? v[1] : v[2]);
    ys[tid] = (vb - mu) * rstd * ln_g[dbase + tid] + ln_b[dbase + tid];
    __syncthreads();

    const float* W = fc_W + (size_t)(dbase + sub * 64) * DOUT + jbase + jt;
    const float* yy = ys + sub * 64;
    float acc = 0.f;
#pragma unroll 8
    for (int i = 0; i < 64; ++i) {
        acc += yy[i] * W[(size_t)i * DOUT];
    }
    part[sub][jt] = acc;
    __syncthreads();
    if (sub == 0) {
        const float tot = part[0][jt] + part[1][jt] + part[2][jt] + part[3][jt];
        atomicAdd(&z[b * DOUT + jbase + jt], tot);
    }
}

// ---------------------------------------------------------------------------
// ln2: add bias, LayerNorm(384) -> out.  grid B, block 384 (6 waves).
// ---------------------------------------------------------------------------
__global__ __launch_bounds__(384) void ln2_kernel(const float* __restrict__ z,
                                                  const float* __restrict__ fc_b,
                                                  const float* __restrict__ ln2_g,
                                                  const float* __restrict__ ln2_b,
                                                  float* __restrict__ out) {
    const int b = blockIdx.x;
    const int tid = threadIdx.x;
    const int lane = tid & 63;
    const int wave = tid >> 6;
    __shared__ float wred[6];

    const float v = z[b * DOUT + tid] + fc_b[tid];

    float s = v;
#pragma unroll
    for (int off = 32; off > 0; off >>= 1) s += __shfl_xor(s, off);
    if (lane == 0) wred[wave] = s;
    __syncthreads();
    float mu = 0.f;
#pragma unroll
    for (int w = 0; w < 6; ++w) mu += wred[w];
    mu /= (float)DOUT;
    __syncthreads();

    const float dd = v - mu;
    float s2 = dd * dd;
#pragma unroll
    for (int off = 32; off > 0; off >>= 1) s2 += __shfl_xor(s2, off);
    if (lane == 0) wred[wave] = s2;
    __syncthreads();
    float var = 0.f;
#pragma unroll
    for (int w = 0; w < 6; ++w) var += wred[w];
    const float rstd = rsqrtf(var / (float)DOUT + EPS);

    out[b * DOUT + tid] = dd * rstd * ln2_g[tid] + ln2_b[tid];
}

extern "C" void kernel_launch(void* const* d_in, const int* in_sizes, int n_in,
                              void* d_out, int out_size, void* d_ws, size_t ws_size,
                              hipStream_t stream) {
    const float* hidden   = (const float*)d_in[0];   // (4,512,768)
    const float* attention= (const float*)d_in[1];   // (4,512,512)
    const float* W_src    = (const float*)d_in[2];
    const float* b_src    = (const float*)d_in[3];
    const float* W_dst    = (const float*)d_in[4];
    const float* b_dst    = (const float*)d_in[5];
    const float* attn_vec = (const float*)d_in[6];
    const float* gat_bias = (const float*)d_in[7];
    const float* gate_W   = (const float*)d_in[8];
    const float* gate_b   = (const float*)d_in[9];
    const float* ln_g     = (const float*)d_in[10];
    const float* ln_b     = (const float*)d_in[11];
    const float* fc_W     = (const float*)d_in[12];
    const float* fc_b     = (const float*)d_in[13];
    const float* ln2_g    = (const float*)d_in[14];
    const float* ln2_b    = (const float*)d_in[15];
    float* out = (float*)d_out;

    const int M = BATCH * LSEQ;           // 2048
    float* feat_dst = (float*)d_ws;                       // M*D fp32
    float* gate     = feat_dst + (size_t)M * D;           // M
    float* pooled   = gate + M;                           // B*D
    float* z        = pooled + BATCH * D;                 // B*DOUT
    ushort_t* Ah    = (ushort_t*)(z + BATCH * DOUT);      // M*D bf16
    ushort_t* WT0   = Ah + (size_t)M * D;                 // D*D bf16 [n][k]
    ushort_t* WT1   = WT0 + (size_t)D * D;                // D*D bf16 [n][k]
    ushort_t* fsrcb = WT1 + (size_t)D * D;                // M*D bf16
    ushort_t* fsrcT = fsrcb + (size_t)M * D;              // M*D bf16 (batch 768x512)
    ushort_t* P     = fsrcT + (size_t)M * D;              // M*LSEQ bf16
    ushort_t* h     = P + (size_t)M * LSEQ;               // M*D bf16

    hipLaunchKernelGGL(prep_kernel, dim3(2689), dim3(256), 0, stream,
                       hidden, Ah, W_src, W_dst, WT0, WT1, pooled, z);
    hipLaunchKernelGGL(feat_gemm_kernel, dim3(D / 64, M / 64, 2), dim3(256), 0, stream,
                       Ah, WT0, b_src, fsrcb, WT1, b_dst, feat_dst);
    hipLaunchKernelGGL(transpose_fsrc_kernel, dim3(D / 32, LSEQ / 32, BATCH), dim3(256), 0, stream,
                       fsrcb, fsrcT);
    hipLaunchKernelGGL(score_kernel, dim3(M), dim3(256), 0, stream,
                       attention, fsrcb, feat_dst, attn_vec, gate_b, P, gate);
    hipLaunchKernelGGL(pgemm_kernel, dim3(D / 64, LSEQ / 64, BATCH), dim3(256), 0, stream,
                       P, fsrcT, gat_bias, hidden, gate_W, h, gate);
    hipLaunchKernelGGL(pool_kernel, dim3(D / 256, LSEQ / 64, BATCH), dim3(256), 0, stream,
                       h, gate, pooled);
    hipLaunchKernelGGL(fc_kernel, dim3(DOUT / 64, D / 256, BATCH), dim3(256), 0, stream,
                       pooled, ln_g, ln_b, fc_W, z);
    hipLaunchKernelGGL(ln2_kernel, dim3(BATCH), dim3(384), 0, stream,
                       z, fc_b, ln2_g, ln2_b, out);
}